// Round 1
// baseline (1120.483 us; speedup 1.0000x reference)
//
#include <hip/hip_runtime.h>
#include <hip/hip_bf16.h>

#define S 1536
#define DM 2880
#define HQ 64
#define HKV 8
#define DH 64
#define NQ (HQ*DH)    /* 4096 */
#define NKV (HKV*DH)  /* 512  */
#define NTOT (NQ + 2*NKV) /* 5120 */
#define SCALE 0.125f
#define NPAD (23*128) /* 2944: DM padded to 128 multiple for out-proj B tiles */

typedef __hip_bfloat16 bf16;
typedef __bf16 bf16x8 __attribute__((ext_vector_type(8)));
typedef float f32x4 __attribute__((ext_vector_type(4)));

__device__ __forceinline__ unsigned short f2bf(float f) {
    unsigned int u = __float_as_uint(f);
    return (unsigned short)((u + 0x7fffu + ((u >> 16) & 1u)) >> 16);
}

// ---------------------------------------------------------------------------
// Cast f32 -> bf16 (grid-stride, float4 vectorized). Elements in [nvalid, n)
// are written as zero (used to pad Wo rows 2880..2943).
// ---------------------------------------------------------------------------
__global__ __launch_bounds__(256) void cast_bf16(
    const float* __restrict__ src, bf16* __restrict__ dst, int n, int nvalid)
{
    const int stride = gridDim.x * 256 * 4;
    for (int i = (blockIdx.x * 256 + threadIdx.x) * 4; i < n; i += stride) {
        float4 v = make_float4(0.f, 0.f, 0.f, 0.f);
        if (i + 4 <= nvalid) v = *(const float4*)(src + i);
        ushort4 pk;
        pk.x = f2bf(v.x); pk.y = f2bf(v.y); pk.z = f2bf(v.z); pk.w = f2bf(v.w);
        *(ushort4*)(dst + i) = pk;
    }
}

// ---------------------------------------------------------------------------
// Shared 128x128 bf16 MFMA GEMM core (A.B^T, both [*][ld] K-contiguous).
// BK=64, 4 waves, each wave owns a 64x64 sub-tile (4x4 frags of 16x16x32).
// Reg-staged global->LDS with XOR chunk swizzle (bank-conflict-free b128
// reads, guide §6 G4) and issue-early prefetch of tile kt+1 under MFMA.
// ---------------------------------------------------------------------------
__device__ __forceinline__ void gemm128_core(
    const bf16* __restrict__ A, const bf16* __restrict__ B,
    const int ld, const int row0, const int col0, const int nk,
    bf16* __restrict__ As, bf16* __restrict__ Bs,
    const int tid, f32x4 acc[4][4])
{
    const int lane = tid & 63;
    const int c16  = lane & 15;
    const int quad = lane >> 4;
    const int w    = tid >> 6;
    const int wr = (w >> 1) * 64, wc = (w & 1) * 64;

    const int rr[4] = { tid >> 3, (256 + tid) >> 3, (512 + tid) >> 3, (768 + tid) >> 3 };
    const int kch = (tid & 7) * 8;

    bf16x8 pa[4], pb[4];
    #pragma unroll
    for (int ci = 0; ci < 4; ++ci) {
        pa[ci] = *(const bf16x8*)(A + (size_t)(row0 + rr[ci]) * ld + kch);
        pb[ci] = *(const bf16x8*)(B + (size_t)(col0 + rr[ci]) * ld + kch);
    }

    for (int kt = 0; kt < nk; ++kt) {
        __syncthreads();
        #pragma unroll
        for (int ci = 0; ci < 4; ++ci) {
            const int byteoff = rr[ci] * 128 + (((tid & 7) ^ (rr[ci] & 7)) * 16);
            *(bf16x8*)((char*)As + byteoff) = pa[ci];
            *(bf16x8*)((char*)Bs + byteoff) = pb[ci];
        }
        __syncthreads();
        if (kt + 1 < nk) {
            const int koff = (kt + 1) * 64 + kch;
            #pragma unroll
            for (int ci = 0; ci < 4; ++ci) {
                pa[ci] = *(const bf16x8*)(A + (size_t)(row0 + rr[ci]) * ld + koff);
                pb[ci] = *(const bf16x8*)(B + (size_t)(col0 + rr[ci]) * ld + koff);
            }
        }
        #pragma unroll
        for (int ksub = 0; ksub < 2; ++ksub) {
            bf16x8 af[4], bv[4];
            const int xorc = ((ksub * 4 + quad) ^ (c16 & 7)) * 16;
            #pragma unroll
            for (int i = 0; i < 4; ++i) {
                af[i] = *(const bf16x8*)((const char*)As + (wr + i*16 + c16)*128 + xorc);
                bv[i] = *(const bf16x8*)((const char*)Bs + (wc + i*16 + c16)*128 + xorc);
            }
            #pragma unroll
            for (int i = 0; i < 4; ++i)
                #pragma unroll
                for (int j = 0; j < 4; ++j)
                    acc[i][j] = __builtin_amdgcn_mfma_f32_16x16x32_bf16(
                        af[i], bv[j], acc[i][j], 0, 0, 0);
        }
    }
}

// ---------------------------------------------------------------------------
// Kernel: fused QKV projection (bf16 MFMA) + bias + RoPE + store.
// C = Xb . Wcat^T. Each wave's 64-col strip is exactly one head, so RoPE
// pairs (d, d+32) live in the SAME lane: acc[i][0]<->acc[i][2],
// acc[i][1]<->acc[i][3]. No LDS exchange needed.
// ---------------------------------------------------------------------------
__global__ __launch_bounds__(256) void qkv_mfma(
    const bf16* __restrict__ Xb, const bf16* __restrict__ Wcat,
    const float* __restrict__ bq, const float* __restrict__ bk,
    const float* __restrict__ bv,
    const float* __restrict__ cosb, const float* __restrict__ sinb,
    bf16* __restrict__ qbf, bf16* __restrict__ kbf, bf16* __restrict__ vbT)
{
    __shared__ bf16 As[128 * 64];
    __shared__ bf16 Bs[128 * 64];
    f32x4 acc[4][4] = {};
    const int tid = threadIdx.x;
    const int row0 = blockIdx.y * 128, col0 = blockIdx.x * 128;

    gemm128_core(Xb, Wcat, DM, row0, col0, DM / 64, As, Bs, tid, acc);

    const int lane = tid & 63, c16 = lane & 15, quad = lane >> 4, w = tid >> 6;
    const int wr = (w >> 1) * 64, wc = (w & 1) * 64;
    const int colbase = col0 + wc;       // multiple of 64 -> one head
    const int srow = row0 + wr + quad * 4;

    if (colbase >= NQ + NKV) {
        // V: bias + transposed bf16 store (4 consecutive s packed per store)
        const int c2 = colbase - NQ - NKV;
        const int hv = c2 >> 6;
        #pragma unroll
        for (int i = 0; i < 4; ++i) {
            const int s0 = srow + i * 16;
            #pragma unroll
            for (int j = 0; j < 4; ++j) {
                const int d = j * 16 + c16;
                const float b = bv[c2 + d];
                ushort4 pk;
                pk.x = f2bf(acc[i][j][0] + b);
                pk.y = f2bf(acc[i][j][1] + b);
                pk.z = f2bf(acc[i][j][2] + b);
                pk.w = f2bf(acc[i][j][3] + b);
                *(ushort4*)(vbT + ((size_t)hv * DH + d) * S + s0) = pk;
            }
        }
        return;
    }

    const bool isK = colbase >= NQ;
    const int cq = isK ? colbase - NQ : colbase;
    const float* bias = isK ? (bk + cq) : (bq + cq);
    bf16* dst = (isK ? kbf : qbf) + (size_t)(cq >> 6) * S * DH;

    #pragma unroll
    for (int i = 0; i < 4; ++i) {
        #pragma unroll
        for (int r = 0; r < 4; ++r) {
            const int s = srow + i * 16 + r;
            const float x1a = acc[i][0][r] + bias[c16];
            const float x1b = acc[i][1][r] + bias[c16 + 16];
            const float x2a = acc[i][2][r] + bias[c16 + 32];
            const float x2b = acc[i][3][r] + bias[c16 + 48];
            const float ca = cosb[s * 32 + c16],      sa = sinb[s * 32 + c16];
            const float cb = cosb[s * 32 + c16 + 16], sb = sinb[s * 32 + c16 + 16];
            bf16* dr = dst + (size_t)s * DH;
            dr[c16]      = __float2bfloat16(x1a * ca - x2a * sa);
            dr[c16 + 32] = __float2bfloat16(x2a * ca + x1a * sa);
            dr[c16 + 16] = __float2bfloat16(x1b * cb - x2b * sb);
            dr[c16 + 48] = __float2bfloat16(x2b * cb + x1b * sb);
        }
    }
}

// ---------------------------------------------------------------------------
// Kernel: MFMA flash attention with sink softmax. Barrier-free: K and V
// fragments load DIRECTLY from global (per-KV-head K/V = 196 KB, L2-resident,
// reused by 8 q-heads x 24 q-tiles -> LDS staging was pure overhead).
// Waves fully independent; only per-wave P round-trip LDS remains.
// ---------------------------------------------------------------------------
__global__ __launch_bounds__(256) void attn_mfma(
    const bf16* __restrict__ qbf, const bf16* __restrict__ kbf,
    const bf16* __restrict__ vbT, const float* __restrict__ sinks,
    float* __restrict__ attn_out,  // [HQ][S][S] f32
    bf16* __restrict__ aobuf)      // [S][HQ*DH] bf16
{
    const int qt = blockIdx.x;     // 0..23
    const int h  = blockIdx.y;     // 0..63
    const int hk = h >> 3;

    __shared__ bf16 Pt[4][16][40]; // per-wave P tile, stride 40 (same-wave RT)

    const int tid  = threadIdx.x;
    const int w    = tid >> 6;
    const int lane = tid & 63;
    const int c16  = lane & 15;
    const int quad = lane >> 4;
    const int q0w  = qt * 64 + w * 16;

    const bf16* qrow = qbf + ((size_t)h * S + q0w + c16) * DH;
    bf16x8 aQ0 = *(const bf16x8*)(qrow + quad * 8);
    bf16x8 aQ1 = *(const bf16x8*)(qrow + 32 + quad * 8);

    const int numtiles = 2 * (qt + 1);
    const float snk_e = __expf(sinks[h]);
    const bf16* kbase = kbf + (size_t)hk * S * DH;
    const bf16* vbase = vbT + (size_t)hk * DH * S;

    // ---------------- pass 1: row sums ----------------
    f32x4 psum = {0.f, 0.f, 0.f, 0.f};
    for (int t = 0; t < numtiles; ++t) {
        const int j0 = t * 32;
        if (j0 > q0w + 15) break;   // tiles monotonic; per-wave early exit
        #pragma unroll
        for (int ct = 0; ct < 2; ++ct) {
            const bf16* kb = kbase + (size_t)(j0 + ct * 16 + c16) * DH + quad * 8;
            bf16x8 b0 = *(const bf16x8*)kb;
            bf16x8 b1 = *(const bf16x8*)(kb + 32);
            f32x4 sc = {0.f, 0.f, 0.f, 0.f};
            sc = __builtin_amdgcn_mfma_f32_16x16x32_bf16(aQ0, b0, sc, 0, 0, 0);
            sc = __builtin_amdgcn_mfma_f32_16x16x32_bf16(aQ1, b1, sc, 0, 0, 0);
            const int jcol = j0 + ct * 16 + c16;
            #pragma unroll
            for (int r = 0; r < 4; ++r) {
                const int qr = q0w + quad * 4 + r;
                psum[r] += (jcol <= qr) ? __expf(sc[r] * SCALE) : 0.f;
            }
        }
    }
    #pragma unroll
    for (int off = 1; off < 16; off <<= 1) {
        psum[0] += __shfl_xor(psum[0], off);
        psum[1] += __shfl_xor(psum[1], off);
        psum[2] += __shfl_xor(psum[2], off);
        psum[3] += __shfl_xor(psum[3], off);
    }
    f32x4 invl;
    #pragma unroll
    for (int r = 0; r < 4; ++r) invl[r] = 1.0f / (psum[r] + snk_e);

    // ---------------- pass 2: probs + P.V ----------------
    f32x4 o[4] = {{0,0,0,0},{0,0,0,0},{0,0,0,0},{0,0,0,0}};
    for (int t = 0; t < numtiles; ++t) {
        const int j0 = t * 32;
        if (j0 > q0w + 15) {
            #pragma unroll
            for (int ct = 0; ct < 2; ++ct)
                #pragma unroll
                for (int r = 0; r < 4; ++r)
                    attn_out[((size_t)h * S + q0w + quad * 4 + r) * S + j0 + ct * 16 + c16] = 0.f;
            continue;
        }
        #pragma unroll
        for (int ct = 0; ct < 2; ++ct) {
            const bf16* kb = kbase + (size_t)(j0 + ct * 16 + c16) * DH + quad * 8;
            bf16x8 b0 = *(const bf16x8*)kb;
            bf16x8 b1 = *(const bf16x8*)(kb + 32);
            f32x4 sc = {0.f, 0.f, 0.f, 0.f};
            sc = __builtin_amdgcn_mfma_f32_16x16x32_bf16(aQ0, b0, sc, 0, 0, 0);
            sc = __builtin_amdgcn_mfma_f32_16x16x32_bf16(aQ1, b1, sc, 0, 0, 0);
            const int jcol = j0 + ct * 16 + c16;
            #pragma unroll
            for (int r = 0; r < 4; ++r) {
                const int qr = q0w + quad * 4 + r;
                const float p = (jcol <= qr) ? __expf(sc[r] * SCALE) * invl[r] : 0.f;
                attn_out[((size_t)h * S + qr) * S + jcol] = p;
                Pt[w][quad * 4 + r][ct * 16 + c16] = __float2bfloat16(p);
            }
        }
        // P tile -> A-layout (same-wave LDS round trip, no barrier needed)
        bf16x8 aP = *(const bf16x8*)((char*)&Pt[w][0][0] + c16 * 80 + quad * 16);
        #pragma unroll
        for (int nt = 0; nt < 4; ++nt) {
            bf16x8 bV = *(const bf16x8*)(vbase + (size_t)(nt * 16 + c16) * S + j0 + quad * 8);
            o[nt] = __builtin_amdgcn_mfma_f32_16x16x32_bf16(aP, bV, o[nt], 0, 0, 0);
        }
    }

    // zero-fill columns beyond this block's causal range
    const int jz0 = 64 * (qt + 1);
    if (jz0 < S) {
        const float4 z4 = make_float4(0.f, 0.f, 0.f, 0.f);
        #pragma unroll
        for (int r = 0; r < 4; ++r) {
            float* row = attn_out + ((size_t)h * S + q0w + quad * 4 + r) * S;
            for (int j = jz0 + c16 * 4; j < S; j += 64)
                *(float4*)(row + j) = z4;
        }
    }

    // write O strip as bf16: [q][h*64 + d]
    #pragma unroll
    for (int r = 0; r < 4; ++r) {
        const int q = q0w + quad * 4 + r;
        bf16* dst = aobuf + (size_t)q * NQ + h * DH;
        #pragma unroll
        for (int nt = 0; nt < 4; ++nt)
            dst[nt * 16 + c16] = __float2bfloat16(o[nt][r]);
    }
}

// ---------------------------------------------------------------------------
// Kernel: output projection (bf16 MFMA). out = aobuf . Wob^T + bo.
// Wob is zero-padded to 2944 rows so N-tiles are uniform; store guarded.
// ---------------------------------------------------------------------------
__global__ __launch_bounds__(256) void out_mfma(
    const bf16* __restrict__ A,    // [S][4096] bf16
    const bf16* __restrict__ Wob,  // [2944][4096] bf16 (rows >=2880 zero)
    const float* __restrict__ bo,
    float* __restrict__ out)       // [S][DM] f32
{
    __shared__ bf16 As[128 * 64];
    __shared__ bf16 Bs[128 * 64];
    f32x4 acc[4][4] = {};
    const int tid = threadIdx.x;
    const int row0 = blockIdx.y * 128, col0 = blockIdx.x * 128;

    gemm128_core(A, Wob, NQ, row0, col0, NQ / 64, As, Bs, tid, acc);

    const int lane = tid & 63, c16 = lane & 15, quad = lane >> 4, w = tid >> 6;
    const int wr = (w >> 1) * 64, wc = (w & 1) * 64;
    #pragma unroll
    for (int i = 0; i < 4; ++i) {
        #pragma unroll
        for (int r = 0; r < 4; ++r) {
            const int s = row0 + wr + i * 16 + quad * 4 + r;
            #pragma unroll
            for (int j = 0; j < 4; ++j) {
                const int c = col0 + wc + j * 16 + c16;
                if (c < DM) out[(size_t)s * DM + c] = acc[i][j][r] + bo[c];
            }
        }
    }
}

// ---------------------------------------------------------------------------
extern "C" void kernel_launch(void* const* d_in, const int* in_sizes, int n_in,
                              void* d_out, int out_size, void* d_ws, size_t ws_size,
                              hipStream_t stream)
{
    const float* hidden = (const float*)d_in[0];
    const float* cosb   = (const float*)d_in[2];
    const float* sinb   = (const float*)d_in[3];
    const float* Wq     = (const float*)d_in[4];
    const float* bq     = (const float*)d_in[5];
    const float* Wk     = (const float*)d_in[6];
    const float* bk     = (const float*)d_in[7];
    const float* Wv     = (const float*)d_in[8];
    const float* bv     = (const float*)d_in[9];
    const float* Wo     = (const float*)d_in[10];
    const float* bo     = (const float*)d_in[11];
    const float* sinks  = (const float*)d_in[12];

    float* out  = (float*)d_out;                     // [S][DM]
    float* attn = out + (size_t)S * DM;              // [HQ][S][S]

    // workspace layout (bf16 elements); Wob reuses Xb+Wcat region after qkv
    bf16* aobuf = (bf16*)d_ws;                       // S*NQ
    bf16* qbf   = aobuf + (size_t)S * NQ;            // HQ*S*DH
    bf16* kbf   = qbf + (size_t)HQ * S * DH;         // HKV*S*DH
    bf16* vbT   = kbf + (size_t)HKV * S * DH;        // HKV*DH*S
    bf16* Xb    = vbT + (size_t)HKV * S * DH;        // S*DM
    bf16* Wcat  = Xb + (size_t)S * DM;               // NTOT*DM
    bf16* Wob   = Xb;                                // NPAD*NQ (fits in Xb+Wcat)

    auto cgrid = [](long n) {
        long b = (n / 4 + 255) / 256;
        return (int)(b > 4096 ? 4096 : b);
    };

    cast_bf16<<<cgrid((long)S * DM), 256, 0, stream>>>(hidden, Xb, S * DM, S * DM);
    cast_bf16<<<cgrid((long)NQ * DM), 256, 0, stream>>>(Wq, Wcat, NQ * DM, NQ * DM);
    cast_bf16<<<cgrid((long)NKV * DM), 256, 0, stream>>>(Wk, Wcat + (size_t)NQ * DM, NKV * DM, NKV * DM);
    cast_bf16<<<cgrid((long)NKV * DM), 256, 0, stream>>>(Wv, Wcat + (size_t)(NQ + NKV) * DM, NKV * DM, NKV * DM);

    dim3 g1(NTOT / 128, S / 128);   // (40, 12)
    qkv_mfma<<<g1, 256, 0, stream>>>(Xb, Wcat, bq, bk, bv, cosb, sinb, qbf, kbf, vbT);

    // Wo cast AFTER qkv (Wob overlaps Xb/Wcat; stream order makes it safe)
    cast_bf16<<<cgrid((long)NPAD * NQ), 256, 0, stream>>>(Wo, Wob, NPAD * NQ, DM * NQ);

    dim3 ga(S / 64, HQ);            // (24, 64)
    attn_mfma<<<ga, 256, 0, stream>>>(qbf, kbf, vbT, sinks, attn, aobuf);

    dim3 g2((DM + 127) / 128, S / 128);  // (23, 12)
    out_mfma<<<g2, 256, 0, stream>>>(aobuf, Wob, bo, out);
}

// Round 4
// 1079.060 us; speedup vs baseline: 1.0384x; 1.0384x over previous
//
#include <hip/hip_runtime.h>
#include <hip/hip_bf16.h>

#define S 1536
#define DM 2880
#define HQ 64
#define HKV 8
#define DH 64
#define NQ (HQ*DH)    /* 4096 */
#define NKV (HKV*DH)  /* 512  */
#define NTOT (NQ + 2*NKV) /* 5120 */
#define SCALE 0.125f
#define NPAD (23*128) /* 2944: DM padded to 128 multiple for out-proj B tiles */

typedef __hip_bfloat16 bf16;
typedef __bf16 bf16x8 __attribute__((ext_vector_type(8)));
typedef float f32x4 __attribute__((ext_vector_type(4)));

__device__ __forceinline__ unsigned short f2bf(float f) {
    unsigned int u = __float_as_uint(f);
    return (unsigned short)((u + 0x7fffu + ((u >> 16) & 1u)) >> 16);
}

// async global->LDS, 16B per lane; LDS dest is wave-uniform base + lane*16
__device__ __forceinline__ void gl_lds16(const bf16* g, bf16* l) {
    __builtin_amdgcn_global_load_lds(
        (const __attribute__((address_space(1))) unsigned int*)g,
        (__attribute__((address_space(3))) unsigned int*)l, 16, 0, 0);
}

// ---------------------------------------------------------------------------
// Cast f32 -> bf16 (grid-stride, float4 vectorized). Elements in [nvalid, n)
// are written as zero (used to pad Wo rows 2880..2943).
// ---------------------------------------------------------------------------
__global__ __launch_bounds__(256) void cast_bf16(
    const float* __restrict__ src, bf16* __restrict__ dst, int n, int nvalid)
{
    const int stride = gridDim.x * 256 * 4;
    for (int i = (blockIdx.x * 256 + threadIdx.x) * 4; i < n; i += stride) {
        float4 v = make_float4(0.f, 0.f, 0.f, 0.f);
        if (i + 4 <= nvalid) v = *(const float4*)(src + i);
        ushort4 pk;
        pk.x = f2bf(v.x); pk.y = f2bf(v.y); pk.z = f2bf(v.z); pk.w = f2bf(v.w);
        *(ushort4*)(dst + i) = pk;
    }
}

// ---------------------------------------------------------------------------
// Shared 128x128 bf16 MFMA GEMM core (A.B^T, both [*][ld] K-contiguous).
// BK=64, 4 waves, each wave owns a 64x64 sub-tile (4x4 frags of 16x16x32).
// Staging: global_load_lds width=16 (m97 structure). LDS dest is linear;
// the XOR chunk swizzle is applied on the per-lane GLOBAL source address
// (involution), and the same XOR on the ds_read_b128 side -> conflict-free
// reads with hardware-path staging (guide rule #21 / m173 pattern).
// ---------------------------------------------------------------------------
__device__ __forceinline__ void gemm128_core(
    const bf16* __restrict__ A, const bf16* __restrict__ B,
    const int ld, const int row0, const int col0, const int nk,
    bf16* As, bf16* Bs, const int tid, f32x4 acc[4][4])
{
    const int lane = tid & 63;
    const int c16  = lane & 15;
    const int quad = lane >> 4;
    const int w    = tid >> 6;
    const int wr = (w >> 1) * 64, wc = (w & 1) * 64;

    // staging geometry: wave w stages rows [w*32, w*32+32) of A and B,
    // 4 instrs each of 8 rows x 128B. lane -> row l>>3, 16B slot l&7.
    const int r_in = lane >> 3;           // 0..7
    const int slot = lane & 7;            // 0..7
    const int csrc = (slot ^ r_in) * 8;   // swizzled source chunk (elements)

    const bf16* Arow[4]; const bf16* Brow[4];
    bf16* Adst[4]; bf16* Bdst[4];
    #pragma unroll
    for (int i = 0; i < 4; ++i) {
        const int rr = w * 32 + i * 8;
        Arow[i] = A + (size_t)(row0 + rr + r_in) * ld + csrc;
        Brow[i] = B + (size_t)(col0 + rr + r_in) * ld + csrc;
        Adst[i] = As + rr * 64;   // wave-uniform LDS base (row*128 bytes)
        Bdst[i] = Bs + rr * 64;
    }

    for (int kt = 0; kt < nk; ++kt) {
        const int koff = kt * 64;
        __syncthreads();   // previous tile's reads done before overwrite
        #pragma unroll
        for (int i = 0; i < 4; ++i) {
            gl_lds16(Arow[i] + koff, Adst[i]);
            gl_lds16(Brow[i] + koff, Bdst[i]);
        }
        __syncthreads();   // vmcnt(0) drain: staged data visible
        #pragma unroll
        for (int ksub = 0; ksub < 2; ++ksub) {
            bf16x8 af[4], bv[4];
            const int xorc = ((ksub * 4 + quad) ^ (c16 & 7)) * 16;
            #pragma unroll
            for (int i = 0; i < 4; ++i) {
                af[i] = *(const bf16x8*)((const char*)As + (wr + i*16 + c16)*128 + xorc);
                bv[i] = *(const bf16x8*)((const char*)Bs + (wc + i*16 + c16)*128 + xorc);
            }
            #pragma unroll
            for (int i = 0; i < 4; ++i)
                #pragma unroll
                for (int j = 0; j < 4; ++j)
                    acc[i][j] = __builtin_amdgcn_mfma_f32_16x16x32_bf16(
                        af[i], bv[j], acc[i][j], 0, 0, 0);
        }
    }
}

// ---------------------------------------------------------------------------
// Kernel: fused QKV projection (bf16 MFMA) + bias + RoPE + store.
// C = Xb . Wcat^T. Each wave's 64-col strip is exactly one head, so RoPE
// pairs (d, d+32) live in the SAME lane: acc[i][0]<->acc[i][2],
// acc[i][1]<->acc[i][3]. No LDS exchange needed.
// ---------------------------------------------------------------------------
__global__ __launch_bounds__(256) void qkv_mfma(
    const bf16* __restrict__ Xb, const bf16* __restrict__ Wcat,
    const float* __restrict__ bq, const float* __restrict__ bk,
    const float* __restrict__ bv,
    const float* __restrict__ cosb, const float* __restrict__ sinb,
    bf16* __restrict__ qbf, bf16* __restrict__ kbf, bf16* __restrict__ vbT)
{
    __shared__ bf16 As[128 * 64];
    __shared__ bf16 Bs[128 * 64];
    f32x4 acc[4][4] = {};
    const int tid = threadIdx.x;
    const int row0 = blockIdx.y * 128, col0 = blockIdx.x * 128;

    gemm128_core(Xb, Wcat, DM, row0, col0, DM / 64, As, Bs, tid, acc);

    const int lane = tid & 63, c16 = lane & 15, quad = lane >> 4, w = tid >> 6;
    const int wr = (w >> 1) * 64, wc = (w & 1) * 64;
    const int colbase = col0 + wc;       // multiple of 64 -> one head
    const int srow = row0 + wr + quad * 4;

    if (colbase >= NQ + NKV) {
        // V: bias + transposed bf16 store (4 consecutive s packed per store)
        const int c2 = colbase - NQ - NKV;
        const int hv = c2 >> 6;
        #pragma unroll
        for (int i = 0; i < 4; ++i) {
            const int s0 = srow + i * 16;
            #pragma unroll
            for (int j = 0; j < 4; ++j) {
                const int d = j * 16 + c16;
                const float b = bv[c2 + d];
                ushort4 pk;
                pk.x = f2bf(acc[i][j][0] + b);
                pk.y = f2bf(acc[i][j][1] + b);
                pk.z = f2bf(acc[i][j][2] + b);
                pk.w = f2bf(acc[i][j][3] + b);
                *(ushort4*)(vbT + ((size_t)hv * DH + d) * S + s0) = pk;
            }
        }
        return;
    }

    const bool isK = colbase >= NQ;
    const int cq = isK ? colbase - NQ : colbase;
    const float* bias = isK ? (bk + cq) : (bq + cq);
    bf16* dst = (isK ? kbf : qbf) + (size_t)(cq >> 6) * S * DH;

    #pragma unroll
    for (int i = 0; i < 4; ++i) {
        #pragma unroll
        for (int r = 0; r < 4; ++r) {
            const int s = srow + i * 16 + r;
            const float x1a = acc[i][0][r] + bias[c16];
            const float x1b = acc[i][1][r] + bias[c16 + 16];
            const float x2a = acc[i][2][r] + bias[c16 + 32];
            const float x2b = acc[i][3][r] + bias[c16 + 48];
            const float ca = cosb[s * 32 + c16],      sa = sinb[s * 32 + c16];
            const float cb = cosb[s * 32 + c16 + 16], sb = sinb[s * 32 + c16 + 16];
            bf16* dr = dst + (size_t)s * DH;
            dr[c16]      = __float2bfloat16(x1a * ca - x2a * sa);
            dr[c16 + 32] = __float2bfloat16(x2a * ca + x1a * sa);
            dr[c16 + 16] = __float2bfloat16(x1b * cb - x2b * sb);
            dr[c16 + 48] = __float2bfloat16(x2b * cb + x1b * sb);
        }
    }
}

// ---------------------------------------------------------------------------
// Kernel: MFMA flash attention with sink softmax. Barrier-free: K and V
// fragments load DIRECTLY from global (per-KV-head K/V = 196 KB, L2-resident,
// reused by 8 q-heads x 24 q-tiles). attn_out stores are NONTEMPORAL so the
// 604 MB write-once probs stream doesn't evict the K/V L2 working set.
// ---------------------------------------------------------------------------
__global__ __launch_bounds__(256) void attn_mfma(
    const bf16* __restrict__ qbf, const bf16* __restrict__ kbf,
    const bf16* __restrict__ vbT, const float* __restrict__ sinks,
    float* __restrict__ attn_out,  // [HQ][S][S] f32
    bf16* __restrict__ aobuf)      // [S][HQ*DH] bf16
{
    const int qt = blockIdx.x;     // 0..23
    const int h  = blockIdx.y;     // 0..63
    const int hk = h >> 3;

    __shared__ bf16 Pt[4][16][40]; // per-wave P tile, stride 40 (same-wave RT)

    const int tid  = threadIdx.x;
    const int w    = tid >> 6;
    const int lane = tid & 63;
    const int c16  = lane & 15;
    const int quad = lane >> 4;
    const int q0w  = qt * 64 + w * 16;

    const bf16* qrow = qbf + ((size_t)h * S + q0w + c16) * DH;
    bf16x8 aQ0 = *(const bf16x8*)(qrow + quad * 8);
    bf16x8 aQ1 = *(const bf16x8*)(qrow + 32 + quad * 8);

    const int numtiles = 2 * (qt + 1);
    const float snk_e = __expf(sinks[h]);
    const bf16* kbase = kbf + (size_t)hk * S * DH;
    const bf16* vbase = vbT + (size_t)hk * DH * S;

    // ---------------- pass 1: row sums ----------------
    f32x4 psum = {0.f, 0.f, 0.f, 0.f};
    for (int t = 0; t < numtiles; ++t) {
        const int j0 = t * 32;
        if (j0 > q0w + 15) break;   // tiles monotonic; per-wave early exit
        #pragma unroll
        for (int ct = 0; ct < 2; ++ct) {
            const bf16* kb = kbase + (size_t)(j0 + ct * 16 + c16) * DH + quad * 8;
            bf16x8 b0 = *(const bf16x8*)kb;
            bf16x8 b1 = *(const bf16x8*)(kb + 32);
            f32x4 sc = {0.f, 0.f, 0.f, 0.f};
            sc = __builtin_amdgcn_mfma_f32_16x16x32_bf16(aQ0, b0, sc, 0, 0, 0);
            sc = __builtin_amdgcn_mfma_f32_16x16x32_bf16(aQ1, b1, sc, 0, 0, 0);
            const int jcol = j0 + ct * 16 + c16;
            #pragma unroll
            for (int r = 0; r < 4; ++r) {
                const int qr = q0w + quad * 4 + r;
                psum[r] += (jcol <= qr) ? __expf(sc[r] * SCALE) : 0.f;
            }
        }
    }
    #pragma unroll
    for (int off = 1; off < 16; off <<= 1) {
        psum[0] += __shfl_xor(psum[0], off);
        psum[1] += __shfl_xor(psum[1], off);
        psum[2] += __shfl_xor(psum[2], off);
        psum[3] += __shfl_xor(psum[3], off);
    }
    f32x4 invl;
    #pragma unroll
    for (int r = 0; r < 4; ++r) invl[r] = 1.0f / (psum[r] + snk_e);

    // ---------------- pass 2: probs + P.V ----------------
    f32x4 o[4] = {{0,0,0,0},{0,0,0,0},{0,0,0,0},{0,0,0,0}};
    for (int t = 0; t < numtiles; ++t) {
        const int j0 = t * 32;
        if (j0 > q0w + 15) {
            #pragma unroll
            for (int ct = 0; ct < 2; ++ct)
                #pragma unroll
                for (int r = 0; r < 4; ++r)
                    __builtin_nontemporal_store(0.f,
                        &attn_out[((size_t)h * S + q0w + quad * 4 + r) * S + j0 + ct * 16 + c16]);
            continue;
        }
        #pragma unroll
        for (int ct = 0; ct < 2; ++ct) {
            const bf16* kb = kbase + (size_t)(j0 + ct * 16 + c16) * DH + quad * 8;
            bf16x8 b0 = *(const bf16x8*)kb;
            bf16x8 b1 = *(const bf16x8*)(kb + 32);
            f32x4 sc = {0.f, 0.f, 0.f, 0.f};
            sc = __builtin_amdgcn_mfma_f32_16x16x32_bf16(aQ0, b0, sc, 0, 0, 0);
            sc = __builtin_amdgcn_mfma_f32_16x16x32_bf16(aQ1, b1, sc, 0, 0, 0);
            const int jcol = j0 + ct * 16 + c16;
            #pragma unroll
            for (int r = 0; r < 4; ++r) {
                const int qr = q0w + quad * 4 + r;
                const float p = (jcol <= qr) ? __expf(sc[r] * SCALE) * invl[r] : 0.f;
                __builtin_nontemporal_store(p, &attn_out[((size_t)h * S + qr) * S + jcol]);
                Pt[w][quad * 4 + r][ct * 16 + c16] = __float2bfloat16(p);
            }
        }
        // P tile -> A-layout (same-wave LDS round trip, no barrier needed)
        bf16x8 aP = *(const bf16x8*)((char*)&Pt[w][0][0] + c16 * 80 + quad * 16);
        #pragma unroll
        for (int nt = 0; nt < 4; ++nt) {
            bf16x8 bV = *(const bf16x8*)(vbase + (size_t)(nt * 16 + c16) * S + j0 + quad * 8);
            o[nt] = __builtin_amdgcn_mfma_f32_16x16x32_bf16(aP, bV, o[nt], 0, 0, 0);
        }
    }

    // zero-fill columns beyond this block's causal range (nontemporal,
    // f32x4 clang vector: __builtin_nontemporal_store rejects HIP float4)
    const int jz0 = 64 * (qt + 1);
    if (jz0 < S) {
        const f32x4 z4 = {0.f, 0.f, 0.f, 0.f};
        #pragma unroll
        for (int r = 0; r < 4; ++r) {
            float* row = attn_out + ((size_t)h * S + q0w + quad * 4 + r) * S;
            for (int j = jz0 + c16 * 4; j < S; j += 64)
                __builtin_nontemporal_store(z4, (f32x4*)(row + j));
        }
    }

    // write O strip as bf16: [q][h*64 + d]
    #pragma unroll
    for (int r = 0; r < 4; ++r) {
        const int q = q0w + quad * 4 + r;
        bf16* dst = aobuf + (size_t)q * NQ + h * DH;
        #pragma unroll
        for (int nt = 0; nt < 4; ++nt)
            dst[nt * 16 + c16] = __float2bfloat16(o[nt][r]);
    }
}

// ---------------------------------------------------------------------------
// Kernel: output projection (bf16 MFMA). out = aobuf . Wob^T + bo.
// Wob is zero-padded to 2944 rows so N-tiles are uniform; store guarded.
// ---------------------------------------------------------------------------
__global__ __launch_bounds__(256) void out_mfma(
    const bf16* __restrict__ A,    // [S][4096] bf16
    const bf16* __restrict__ Wob,  // [2944][4096] bf16 (rows >=2880 zero)
    const float* __restrict__ bo,
    float* __restrict__ out)       // [S][DM] f32
{
    __shared__ bf16 As[128 * 64];
    __shared__ bf16 Bs[128 * 64];
    f32x4 acc[4][4] = {};
    const int tid = threadIdx.x;
    const int row0 = blockIdx.y * 128, col0 = blockIdx.x * 128;

    gemm128_core(A, Wob, NQ, row0, col0, NQ / 64, As, Bs, tid, acc);

    const int lane = tid & 63, c16 = lane & 15, quad = lane >> 4, w = tid >> 6;
    const int wr = (w >> 1) * 64, wc = (w & 1) * 64;
    #pragma unroll
    for (int i = 0; i < 4; ++i) {
        #pragma unroll
        for (int r = 0; r < 4; ++r) {
            const int s = row0 + wr + i * 16 + quad * 4 + r;
            #pragma unroll
            for (int j = 0; j < 4; ++j) {
                const int c = col0 + wc + j * 16 + c16;
                if (c < DM) out[(size_t)s * DM + c] = acc[i][j][r] + bo[c];
            }
        }
    }
}

// ---------------------------------------------------------------------------
extern "C" void kernel_launch(void* const* d_in, const int* in_sizes, int n_in,
                              void* d_out, int out_size, void* d_ws, size_t ws_size,
                              hipStream_t stream)
{
    const float* hidden = (const float*)d_in[0];
    const float* cosb   = (const float*)d_in[2];
    const float* sinb   = (const float*)d_in[3];
    const float* Wq     = (const float*)d_in[4];
    const float* bq     = (const float*)d_in[5];
    const float* Wk     = (const float*)d_in[6];
    const float* bk     = (const float*)d_in[7];
    const float* Wv     = (const float*)d_in[8];
    const float* bv     = (const float*)d_in[9];
    const float* Wo     = (const float*)d_in[10];
    const float* bo     = (const float*)d_in[11];
    const float* sinks  = (const float*)d_in[12];

    float* out  = (float*)d_out;                     // [S][DM]
    float* attn = out + (size_t)S * DM;              // [HQ][S][S]

    // workspace layout (bf16 elements); Wob reuses Xb+Wcat region after qkv
    bf16* aobuf = (bf16*)d_ws;                       // S*NQ
    bf16* qbf   = aobuf + (size_t)S * NQ;            // HQ*S*DH
    bf16* kbf   = qbf + (size_t)HQ * S * DH;         // HKV*S*DH
    bf16* vbT   = kbf + (size_t)HKV * S * DH;        // HKV*DH*S
    bf16* Xb    = vbT + (size_t)HKV * S * DH;        // S*DM
    bf16* Wcat  = Xb + (size_t)S * DM;               // NTOT*DM
    bf16* Wob   = Xb;                                // NPAD*NQ (fits in Xb+Wcat)

    auto cgrid = [](long n) {
        long b = (n / 4 + 255) / 256;
        return (int)(b > 4096 ? 4096 : b);
    };

    cast_bf16<<<cgrid((long)S * DM), 256, 0, stream>>>(hidden, Xb, S * DM, S * DM);
    cast_bf16<<<cgrid((long)NQ * DM), 256, 0, stream>>>(Wq, Wcat, NQ * DM, NQ * DM);
    cast_bf16<<<cgrid((long)NKV * DM), 256, 0, stream>>>(Wk, Wcat + (size_t)NQ * DM, NKV * DM, NKV * DM);
    cast_bf16<<<cgrid((long)NKV * DM), 256, 0, stream>>>(Wv, Wcat + (size_t)(NQ + NKV) * DM, NKV * DM, NKV * DM);

    dim3 g1(NTOT / 128, S / 128);   // (40, 12)
    qkv_mfma<<<g1, 256, 0, stream>>>(Xb, Wcat, bq, bk, bv, cosb, sinb, qbf, kbf, vbT);

    // Wo cast AFTER qkv (Wob overlaps Xb/Wcat; stream order makes it safe)
    cast_bf16<<<cgrid((long)NPAD * NQ), 256, 0, stream>>>(Wo, Wob, NPAD * NQ, DM * NQ);

    dim3 ga(S / 64, HQ);            // (24, 64)
    attn_mfma<<<ga, 256, 0, stream>>>(qbf, kbf, vbT, sinks, attn, aobuf);

    dim3 g2((DM + 127) / 128, S / 128);  // (23, 12)
    out_mfma<<<g2, 256, 0, stream>>>(aobuf, Wob, bo, out);
}